// Round 12
// baseline (1046.479 us; speedup 1.0000x reference)
//
#include <hip/hip_runtime.h>
#include <hip/hip_bf16.h>
#include <hip/hip_cooperative_groups.h>
#include <math.h>

namespace cg = cooperative_groups;

#define NB 32
#define NN 512
#define GIN 192
#define ATT 384
#define EPSF 1e-11f

typedef __attribute__((ext_vector_type(4))) float f32x4;
typedef __attribute__((ext_vector_type(8))) short short8;

__device__ __forceinline__ ushort bfhi(float f) {
    uint u = __float_as_uint(f);
    return (ushort)((u + 0x7FFFu + ((u >> 16) & 1u)) >> 16);
}
__device__ __forceinline__ float bff(ushort h) {
    return __uint_as_float(((uint)h) << 16);
}
__device__ __forceinline__ void bfsplit(float f, ushort& hi, ushort& lo) {
    hi = bfhi(f);
    lo = bfhi(f - bff(hi));
}

// ================= k_front: prep (nbr/deg/dinv/mask) + gather + weight transposes =================
__global__ __launch_bounds__(256) void k_front(
    const float* __restrict__ adj, ushort* __restrict__ nbr, int* __restrict__ deg,
    float* __restrict__ dinv, float* __restrict__ mask,
    const int* __restrict__ n0, const int* __restrict__ n1, const int* __restrict__ n2,
    const float* __restrict__ e0, const float* __restrict__ e1, const float* __restrict__ e2,
    ushort* __restrict__ fh, ushort* __restrict__ fl,
    const float* __restrict__ gw0, const float* __restrict__ gw1,
    const float* __restrict__ gw2, const float* __restrict__ aw1,
    ushort* __restrict__ t0h, ushort* __restrict__ t0l,
    ushort* __restrict__ t1h, ushort* __restrict__ t1l,
    ushort* __restrict__ t2h, ushort* __restrict__ t2l,
    ushort* __restrict__ tah, ushort* __restrict__ tal) {
    __shared__ float tile[32][33];
    int blk = blockIdx.x, t = threadIdx.x;
    if (blk < 4096) {
        // prep: 4 rows/block, one wave per row (ballot compaction wave-local)
        int row = blk * 4 + (t >> 6);
        int lane = t & 63;
        const float* a = adj + (size_t)row * NN;
        float4 v0 = ((const float4*)a)[lane * 2];
        float4 v1 = ((const float4*)a)[lane * 2 + 1];
        float vv[8] = {v0.x, v0.y, v0.z, v0.w, v1.x, v1.y, v1.z, v1.w};
        float s = 0.f, m = 0.f;
        int cnt = 0;
        unsigned long long below = (lane == 63) ? 0xFFFFFFFFFFFFFFFFULL >> 1
                                                : ((1ULL << lane) - 1ULL);
#pragma unroll
        for (int e = 0; e < 8; e++) {
            float v = vv[e];
            s += v;
            m = fmaxf(m, v);
            bool nz = v != 0.f;
            unsigned long long bm = __ballot(nz);
            int pos = cnt + __popcll(bm & below);
            if (nz && pos < 64) nbr[(size_t)row * 64 + pos] = (ushort)(lane * 8 + e);
            cnt += __popcll(bm);
        }
        for (int off = 32; off; off >>= 1) {
            s += __shfl_xor(s, off);
            m = fmaxf(m, __shfl_xor(m, off));
        }
        if (lane == 0) {
            deg[row] = cnt < 64 ? cnt : 64;
            dinv[row] = s > 0.f ? 1.0f / sqrtf(s) : 0.f;
            mask[row] = m;
        }
    } else if (blk < 16384) {
        int tid = (blk - 4096) * 256 + t;   // exactly NB*NN*GIN
        int bn = tid / GIN, f = tid - bn * GIN;
        float v;
        if (f < 64)       v = e0[n0[bn] * 64 + f];
        else if (f < 128) v = e1[n1[bn] * 64 + (f - 64)];
        else              v = e2[n2[bn] * 64 + (f - 128)];
        ushort h, lo;
        bfsplit(v, h, lo);
        fh[tid] = h; fl[tid] = lo;
    } else {
        int job = blk - 16384;  // < 576 = 4*144
        int z = job / 144, rem = job % 144;
        int k0 = (rem / 12) * 32, nn0 = (rem % 12) * 32;
        const float* W; ushort *Th, *Tl; int K, N;
        switch (z) {
            case 0: W = gw0; Th = t0h; Tl = t0l; K = 192; N = 128; break;
            case 1: W = gw1; Th = t1h; Tl = t1l; K = 128; N = 128; break;
            case 2: W = gw2; Th = t2h; Tl = t2l; K = 128; N = 128; break;
            default: W = aw1; Th = tah; Tl = tal; K = 384; N = 384; break;
        }
        if (k0 >= K || nn0 >= N) return;
        int tx = t & 31, ty = t >> 5;
#pragma unroll
        for (int r = 0; r < 4; r++)
            tile[ty + r * 8][tx] = W[(size_t)(k0 + ty + r * 8) * N + nn0 + tx];
        __syncthreads();
#pragma unroll
        for (int r = 0; r < 4; r++) {
            int nn = ty + r * 8;
            float v = tile[tx][nn];
            ushort h, lo;
            bfsplit(v, h, lo);
            size_t o = (size_t)(nn0 + nn) * K + k0 + tx;
            Th[o] = h; Tl[o] = lo;
        }
    }
}

// ================= MFMA split-bf16 GEMM: BM=64 x BN=128 (verified r11) =================
template <int KK, int EPI>
__global__ __launch_bounds__(256) void k_mfg(
    const ushort* __restrict__ Ah, const ushort* __restrict__ Al, int lda,
    const ushort* __restrict__ Bh, const ushort* __restrict__ Bl,
    const float* __restrict__ bias, const float* __restrict__ dinv,
    float* __restrict__ Of, const float* __restrict__ aw2p) {
    __shared__ ushort Ash[2048], Asl[2048];
    __shared__ ushort Bsh[4096], Bsl[4096];
    __shared__ float ep[(EPI == 0) ? 64 * 128 : 1];
    int t = threadIdx.x;
    int bid = blockIdx.x;
    {
        int q = gridDim.x >> 3;
        bid = (bid & 7) * q + (bid >> 3);
    }
    int m0 = bid * 64;
    int n0 = blockIdx.y * 128;
    int l = t & 63, w = t >> 6, wr = w >> 1, wc = w & 1;
    int rA = t >> 2, kc = t & 3;
    int rB0 = rA, rB1 = rA + 64;
    int lsA  = ((rA >> 4) * 64 + (rA & 15) + kc * 16) * 8;
    int lsB0 = ((rB0 >> 4) * 64 + (rB0 & 15) + kc * 16) * 8;
    int lsB1 = ((rB1 >> 4) * 64 + (rB1 & 15) + kc * 16) * 8;
    f32x4 z = {0.f, 0.f, 0.f, 0.f};
    f32x4 acc[2][4];
#pragma unroll
    for (int i = 0; i < 2; i++)
#pragma unroll
        for (int j = 0; j < 4; j++) acc[i][j] = z;

    short8 pa0, pal0, pb0, pb1, pbl0, pbl1;
    int kof = kc * 8;
    {
        pa0 = *(const short8*)&Ah[(size_t)(m0 + rA) * lda + kof];
        pal0 = *(const short8*)&Al[(size_t)(m0 + rA) * lda + kof];
        pb0 = *(const short8*)&Bh[(size_t)(n0 + rB0) * KK + kof];
        pb1 = *(const short8*)&Bh[(size_t)(n0 + rB1) * KK + kof];
        pbl0 = *(const short8*)&Bl[(size_t)(n0 + rB0) * KK + kof];
        pbl1 = *(const short8*)&Bl[(size_t)(n0 + rB1) * KK + kof];
    }
    for (int k0 = 0; k0 < KK; k0 += 32) {
        *(short8*)&Ash[lsA] = pa0;
        *(short8*)&Asl[lsA] = pal0;
        *(short8*)&Bsh[lsB0] = pb0;
        *(short8*)&Bsh[lsB1] = pb1;
        *(short8*)&Bsl[lsB0] = pbl0;
        *(short8*)&Bsl[lsB1] = pbl1;
        __syncthreads();
        if (k0 + 32 < KK) {
            int kn = k0 + 32 + kof;
            pa0 = *(const short8*)&Ah[(size_t)(m0 + rA) * lda + kn];
            pal0 = *(const short8*)&Al[(size_t)(m0 + rA) * lda + kn];
            pb0 = *(const short8*)&Bh[(size_t)(n0 + rB0) * KK + kn];
            pb1 = *(const short8*)&Bh[(size_t)(n0 + rB1) * KK + kn];
            pbl0 = *(const short8*)&Bl[(size_t)(n0 + rB0) * KK + kn];
            pbl1 = *(const short8*)&Bl[(size_t)(n0 + rB1) * KK + kn];
        }
        short8 ah[2], al[2], bh[4], bl[4];
#pragma unroll
        for (int i = 0; i < 2; i++) {
            ah[i] = *(const short8*)&Ash[((wr * 2 + i) * 64 + l) * 8];
            al[i] = *(const short8*)&Asl[((wr * 2 + i) * 64 + l) * 8];
        }
#pragma unroll
        for (int j = 0; j < 4; j++) {
            bh[j] = *(const short8*)&Bsh[((wc * 4 + j) * 64 + l) * 8];
            bl[j] = *(const short8*)&Bsl[((wc * 4 + j) * 64 + l) * 8];
        }
#pragma unroll
        for (int i = 0; i < 2; i++)
#pragma unroll
            for (int j = 0; j < 4; j++) {
                acc[i][j] = __builtin_amdgcn_mfma_f32_16x16x32_bf16(ah[i], bh[j], acc[i][j], 0, 0, 0);
                acc[i][j] = __builtin_amdgcn_mfma_f32_16x16x32_bf16(ah[i], bl[j], acc[i][j], 0, 0, 0);
                acc[i][j] = __builtin_amdgcn_mfma_f32_16x16x32_bf16(al[i], bh[j], acc[i][j], 0, 0, 0);
            }
        __syncthreads();
    }
    if constexpr (EPI == 3) {
#pragma unroll
        for (int i = 0; i < 2; i++) {
            float rs[4] = {0.f, 0.f, 0.f, 0.f};
#pragma unroll
            for (int j = 0; j < 4; j++) {
                int gc = n0 + (wc * 4 + j) * 16 + (l & 15);
                float bv = bias[gc], wv = aw2p[gc];
#pragma unroll
                for (int r = 0; r < 4; r++)
                    rs[r] += tanhf(acc[i][j][r] + bv) * wv;
            }
#pragma unroll
            for (int r = 0; r < 4; r++) {
                rs[r] += __shfl_xor(rs[r], 1, 16);
                rs[r] += __shfl_xor(rs[r], 2, 16);
                rs[r] += __shfl_xor(rs[r], 4, 16);
                rs[r] += __shfl_xor(rs[r], 8, 16);
            }
            if ((l & 15) == 0) {
                int gr0 = m0 + (wr * 2 + i) * 16 + 4 * (l >> 4);
#pragma unroll
                for (int r = 0; r < 4; r++) atomicAdd(&Of[gr0 + r], rs[r]);
            }
        }
    } else {
#pragma unroll
        for (int i = 0; i < 2; i++)
#pragma unroll
            for (int j = 0; j < 4; j++) {
                int lc = (wc * 4 + j) * 16 + (l & 15);
                int lr0 = (wr * 2 + i) * 16 + 4 * (l >> 4);
                float bv = bias[lc];
#pragma unroll
                for (int r = 0; r < 4; r++)
                    ep[(lr0 + r) * 128 + lc] = (acc[i][j][r] + bv) * dinv[m0 + lr0 + r];
            }
        __syncthreads();
        int row = t >> 2, c0 = (t & 3) * 32;
        size_t ob = (size_t)(m0 + row) * 128 + c0;
#pragma unroll
        for (int k = 0; k < 8; k++)
            ((float4*)&Of[ob])[k] = *(const float4*)&ep[row * 128 + c0 + k * 4];
    }
}

// ------- sparse adj gather (verified r11): 1024 blocks, 16 rows each -------
__global__ __launch_bounds__(256) void k_adjsp(const ushort* __restrict__ nbr,
                                               const int* __restrict__ deg,
                                               const float* __restrict__ Y,
                                               const float* __restrict__ dinv,
                                               ushort* __restrict__ Hbh,
                                               ushort* __restrict__ Hbl, int hoff) {
    int bid = blockIdx.x;
    {
        int q = gridDim.x >> 3;
        bid = (bid & 7) * q + (bid >> 3);
    }
    int b = bid >> 5;
    int rg = bid & 31;
    int base = b * NN + rg * 16;
    __shared__ ushort nl[16 * 64];
    __shared__ int dl[16];
    int t = threadIdx.x;
    if (t < 128) *(short8*)&nl[t * 8] = *(const short8*)&nbr[(size_t)base * 64 + t * 8];
    if (t < 16) dl[t] = deg[base + t];
    __syncthreads();
    int row = t >> 4, c0 = (t & 15) * 8;
    const float* yp = Y + (size_t)b * 65536 + c0;
    float acc[8] = {0.f, 0.f, 0.f, 0.f, 0.f, 0.f, 0.f, 0.f};
    int dg = dl[row];
    const ushort* nr = &nl[row * 64];
    for (int q = 0; q < dg; q++) {
        const float4* y = (const float4*)(yp + (int)nr[q] * 128);
        float4 a = y[0], c = y[1];
        acc[0] += a.x; acc[1] += a.y; acc[2] += a.z; acc[3] += a.w;
        acc[4] += c.x; acc[5] += c.y; acc[6] += c.z; acc[7] += c.w;
    }
    float dv = dinv[base + row];
    short8 vh, vl;
#pragma unroll
    for (int c = 0; c < 8; c++) {
        float v = tanhf(acc[c] * dv);
        ushort h, lo;
        bfsplit(v, h, lo);
        vh[c] = (short)h; vl[c] = (short)lo;
    }
    size_t o = (size_t)(base + row) * ATT + hoff + c0;
    *(short8*)&Hbh[o] = vh;
    *(short8*)&Hbl[o] = vl;
}

// ================= cooperative routing mega-kernel =================
struct RArgs {
    float* logit; const float* maskp; float* numn;
    const ushort* Hbh; const ushort* Hbl;
    float* G0; const float* Wg; float* vg; float* Wv;
    float* bij; float* Gs; float* u2g; const float* Wc;
    const int* label; const float* recon;
    const float* rw1; const float* rb1; const float* rw2; const float* rb2;
    float* out; float* marg; float* recl;
};

__device__ void ph_attnsm(const RArgs& a, int b, int t, float* pool) {
    float* red = pool; float* red2 = pool + 4; float* red3 = pool + 8;
    float mk0 = a.maskp[b * NN + t], mk1 = a.maskp[b * NN + 256 + t];
    float x0 = mk0 > 0.f ? a.logit[b * NN + t] : -INFINITY;
    float x1 = mk1 > 0.f ? a.logit[b * NN + 256 + t] : -INFINITY;
    float m = fmaxf(x0, x1), ns = mk0 + mk1;
    for (int off = 32; off; off >>= 1) {
        m = fmaxf(m, __shfl_xor(m, off));
        ns += __shfl_xor(ns, off);
    }
    if ((t & 63) == 0) { red[t >> 6] = m; red3[t >> 6] = ns; }
    __syncthreads();
    float gm = fmaxf(fmaxf(red[0], red[1]), fmaxf(red[2], red[3]));
    float nn = red3[0] + red3[1] + red3[2] + red3[3];
    float e0 = expf(x0 - gm), e1 = expf(x1 - gm);
    float s = e0 + e1;
    for (int off = 32; off; off >>= 1) s += __shfl_xor(s, off);
    if ((t & 63) == 0) red2[t >> 6] = s;
    __syncthreads();
    float gs = red2[0] + red2[1] + red2[2] + red2[3];
    a.logit[b * NN + t] = (e0 / gs) * nn;
    a.logit[b * NN + 256 + t] = (e1 / gs) * nn;
    if (t == 0) a.numn[b] = nn;
    __syncthreads();
}

__device__ void ph_Hsum(const RArgs& a, int job, int t, float* pool) {
    int c = job % 6, b = job / 6;
    int i = t & 63, gq = t >> 6;
    float s = 0.f;
    for (int n = gq * 128; n < gq * 128 + 128; n++) {
        size_t o = ((size_t)b * NN + n) * ATT + c * 64 + i;
        s += a.logit[b * NN + n] * (bff(a.Hbh[o]) + bff(a.Hbl[o]));
    }
    float* red = pool;
    red[t] = s;
    __syncthreads();
    if (t < 128) red[t] += red[t + 128];
    __syncthreads();
    if (t < 64) a.G0[(size_t)job * 64 + i] = red[t] + red[t + 64];
    __syncthreads();
}

template <int SRC, bool DOWV>
__device__ void ph_SVj(const RArgs& a, int b, int j, int t, float* pool) {
    float* Wgl = pool;            // 12672
    float* gj  = pool + 12672;    // 384
    float* red = pool + 13056;    // 256
    float* vvs = pool + 13312;    // 32
    for (int idx = t; idx < 12288; idx += 256) {
        int r = idx >> 5, d = idx & 31;
        Wgl[r * 33 + d] = a.Wg[(size_t)r * 512 + j * 32 + d];
    }
    for (int r = t; r < 384; r += 256) {
        if constexpr (SRC == 0) {
            gj[r] = a.G0[b * 384 + r] * (1.f / 16.f);
        } else {
            const float* gp = a.Gs + ((size_t)b * 6 + (r >> 6)) * 4096 + j * 64 + (r & 63);
            gj[r] = gp[0] + gp[1024] + gp[2048] + gp[3072];
        }
    }
    __syncthreads();
    int d = t & 31, g8 = t >> 5;
    float pp = 0.f;
#pragma unroll
    for (int k = 0; k < 48; k++) {
        int r = g8 * 48 + k;
        pp += gj[r] * Wgl[r * 33 + d];
    }
    red[t] = pp;
    __syncthreads();
    if (t < 128) red[t] += red[t + 128];
    __syncthreads();
    if (t < 64) red[t] += red[t + 64];
    __syncthreads();
    if (t < 32) {
        float s = (red[t] + red[t + 32]) / a.numn[b];
        float sq = s * s;
        for (int off = 16; off; off >>= 1) sq += __shfl_xor(sq, off, 32);
        float v = (sq / (1.f + sq)) * s / sqrtf(sq + EPSF);
        vvs[t] = v;
        a.vg[(size_t)b * 512 + j * 32 + t] = v;
    }
    __syncthreads();
    if constexpr (DOWV) {
        for (int r = t; r < 384; r += 256) {
            float s2 = 0.f;
#pragma unroll
            for (int d2 = 0; d2 < 32; d2++) s2 += Wgl[r * 33 + d2] * vvs[d2];
            a.Wv[(size_t)b * 6144 + (r >> 6) * 1024 + (r & 63) * 16 + j] = s2;
        }
    }
    __syncthreads();
}

template <bool ACC>
__device__ void ph_bup16(const RArgs& a, int job, int t, float* pool) {
    int b = job >> 5;
    int n0 = (job & 31) * 16;
    float* wl = pool;          // 6144
    float* hl = pool + 6144;   // 6144 (16 rows x 384)
    for (int idx = t; idx < 6144; idx += 256) wl[idx] = a.Wv[(size_t)b * 6144 + idx];
    for (int idx = t; idx < 6144; idx += 256) {
        int nn = idx / ATT;
        size_t o = ((size_t)b * NN + n0) * ATT + idx;
        hl[idx] = a.logit[b * NN + n0 + nn] * (bff(a.Hbh[o]) + bff(a.Hbl[o]));
    }
    __syncthreads();
    for (int idx = t; idx < 1536; idx += 256) {
        int nn = idx / 96, r = idx % 96, c = r >> 4, j = r & 15;
        float s = 0.f;
        const float* h = hl + nn * ATT + c * 64;
        const float* w = wl + c * 1024 + j;
#pragma unroll
        for (int i2 = 0; i2 < 64; i2++) s += h[i2] * w[i2 * 16];
        size_t o = (((size_t)b * NN + n0 + nn) * 6 + c) * 16 + j;
        if constexpr (ACC) a.bij[o] += s;
        else a.bij[o] = s;
    }
    __syncthreads();
}

__device__ void ph_GsSM(const RArgs& a, int job, int t, float* pool) {
    int seg = job & 3, c = (job >> 2) % 6, b = job / 24;
    float* ct = pool;         // 256
    float* ht = pool + 256;   // 1024
    int i = t & 63, j0 = t >> 6;
    float acc[4] = {0.f, 0.f, 0.f, 0.f};
    int n0 = seg * 128;
    for (int nc = 0; nc < 128; nc += 16) {
        {
            int nn = t >> 4;
            float v = a.bij[(((size_t)b * NN + n0 + nc + nn) * 6 + c) * 16 + (t & 15)];
            float mx = v;
            mx = fmaxf(mx, __shfl_xor(mx, 1, 16));
            mx = fmaxf(mx, __shfl_xor(mx, 2, 16));
            mx = fmaxf(mx, __shfl_xor(mx, 4, 16));
            mx = fmaxf(mx, __shfl_xor(mx, 8, 16));
            float e = expf(v - mx);
            float sm = e;
            sm += __shfl_xor(sm, 1, 16);
            sm += __shfl_xor(sm, 2, 16);
            sm += __shfl_xor(sm, 4, 16);
            sm += __shfl_xor(sm, 8, 16);
            ct[t] = e / sm;
        }
        for (int idx = t; idx < 1024; idx += 256) {
            int nn = idx >> 6, ii = idx & 63;
            int n = n0 + nc + nn;
            size_t o = ((size_t)b * NN + n) * ATT + c * 64 + ii;
            ht[idx] = a.logit[b * NN + n] * (bff(a.Hbh[o]) + bff(a.Hbl[o]));
        }
        __syncthreads();
        for (int nn = 0; nn < 16; nn++) {
            float hv = ht[nn * 64 + i];
#pragma unroll
            for (int q = 0; q < 4; q++) acc[q] += ct[nn * 16 + j0 * 4 + q] * hv;
        }
        __syncthreads();
    }
#pragma unroll
    for (int q = 0; q < 4; q++) {
        int j = j0 * 4 + q;
        a.Gs[(((size_t)b * 6 + c) * 4 + seg) * 1024 + j * 64 + i] = acc[q];
    }
}

__device__ void ph_u2(const RArgs& a, int c, int t, float* pool) {
    float* Wcl = pool;          // 6144
    float* vgl = pool + 6144;   // 1024
    for (int idx = t; idx < 6144; idx += 256) Wcl[idx] = a.Wc[(size_t)c * 6144 + idx];
    for (int idx = t; idx < 1024; idx += 256) {
        int b = idx >> 5, i2 = idx & 31;
        vgl[idx] = a.vg[(size_t)b * 512 + c * 32 + i2];
    }
    __syncthreads();
    for (int o = t; o < 6144; o += 256) {
        int b = o / 192, jd = o - b * 192;
        float s = 0.f;
#pragma unroll
        for (int i2 = 0; i2 < 32; i2++) s += vgl[b * 32 + i2] * Wcl[i2 * 192 + jd];
        a.u2g[(size_t)b * 3072 + c * 192 + jd] = s;
    }
    __syncthreads();
}

__device__ void ph_caps2(const RArgs& a, int b, int t, float* pool) {
    float* u2   = pool;          // 3072
    float* b2   = pool + 3072;   // 96
    float* c2b  = pool + 3168;   // 96
    float* vv   = pool + 3264;   // 192
    float* magl = pool + 3456;   // 6
    float* cm   = pool + 3462;   // 32
    float* hidl = pool + 3494;   // 128
    float* red  = pool + 3622;   // 256
    for (int idx = t; idx < 3072; idx += 256) u2[idx] = a.u2g[(size_t)b * 3072 + idx];
    if (t < 96) b2[t] = 0.f;
    __syncthreads();
    for (int it = 0; it < 3; it++) {
        if (t < 16) {
            float mx = -INFINITY;
            for (int j = 0; j < 6; j++) mx = fmaxf(mx, b2[t * 6 + j]);
            float e[6], s = 0.f;
            for (int j = 0; j < 6; j++) { e[j] = expf(b2[t * 6 + j] - mx); s += e[j]; }
            for (int j = 0; j < 6; j++) c2b[t * 6 + j] = e[j] / s;
        }
        __syncthreads();
        if (t < 192) {
            int j = t >> 5, d = t & 31;
            float s = 0.f;
            for (int c = 0; c < 16; c++) s += c2b[c * 6 + j] * u2[c * 192 + j * 32 + d];
            float sq = s * s;
            for (int off = 16; off; off >>= 1) sq += __shfl_xor(sq, off, 32);
            vv[t] = (sq / (1.f + sq)) * s / sqrtf(sq + EPSF);
        }
        __syncthreads();
        if (it < 2) {
            if (t < 96) {
                int c = t / 6, j = t - c * 6;
                float s = 0.f;
                for (int d = 0; d < 32; d++) s += u2[c * 192 + j * 32 + d] * vv[j * 32 + d];
                b2[t] += s;
            }
            __syncthreads();
        }
    }
    if (t < 192) a.out[(size_t)b * 192 + t] = vv[t];
    if (t < 6) {
        float s = 0.f;
        for (int d = 0; d < 32; d++) { float v = vv[t * 32 + d]; s += v * v; }
        magl[t] = sqrtf(s);
    }
    __syncthreads();
    int lab = a.label[b];
    if (t == 0) {
        float L = 0.f;
        int pbest = 0;
        float best = magl[0];
        for (int j = 0; j < 6; j++) {
            float mg = magl[j];
            if (mg > best) { best = mg; pbest = j; }
            float ml = fmaxf(0.9f - mg, 0.f); ml *= ml;
            float mr = fmaxf(mg - 0.1f, 0.f); mr *= mr;
            L += (j == lab) ? ml : 0.5f * mr;
        }
        a.marg[b] = L;
        a.out[6147 + b] = (float)pbest;
    }
    if (t < 32) cm[t] = vv[lab * 32 + t];
    __syncthreads();
    if (t < 128) {
        float s = a.rb1[t];
        for (int d = 0; d < 32; d++) s += cm[d] * a.rw1[d * 128 + t];
        hidl[t] = fmaxf(s, 0.f);
    }
    __syncthreads();
    bool act = t < 208;
    float rv = 0.f, rin = 0.f;
    if (act) {
        float s = a.rb2[t];
        for (int k = 0; k < 128; k++) s += hidl[k] * a.rw2[k * 208 + t];
        rv = 1.f / (1.f + expf(-s));
        rin = a.recon[(size_t)b * 208 + t];
    }
    red[t] = act ? rin : -INFINITY;
    __syncthreads();
    for (int s2 = 128; s2; s2 >>= 1) {
        if (t < s2) red[t] = fmaxf(red[t], red[t + s2]);
        __syncthreads();
    }
    float rmax = red[0];
    __syncthreads();
    float dpos = 0.f, dneg = 0.f;
    if (act) {
        float rec_val = rin / (rmax + EPSF);
        float d2 = rv - rec_val; d2 *= d2;
        bool neg = rin < 1e-5f;
        dpos = neg ? 0.f : d2;
        dneg = neg ? d2 : 0.f;
    }
    red[t] = dpos;
    __syncthreads();
    for (int s2 = 128; s2; s2 >>= 1) {
        if (t < s2) red[t] = fmaxf(red[t], red[t + s2]);
        __syncthreads();
    }
    float mp = red[0];
    __syncthreads();
    red[t] = dneg;
    __syncthreads();
    for (int s2 = 128; s2; s2 >>= 1) {
        if (t < s2) red[t] = fmaxf(red[t], red[t + s2]);
        __syncthreads();
    }
    if (t == 0) a.recl[b] = mp + red[0];
}

__device__ void ph_final(const RArgs& a, int t) {
    if (t < 32) {
        float m = a.marg[t], r = a.recl[t];
        for (int off = 16; off; off >>= 1) {
            m += __shfl_xor(m, off, 32);
            r += __shfl_xor(r, off, 32);
        }
        if (t == 0) {
            m /= 32.f;
            r /= 32.f;
            a.out[6144] = m + 0.1f * r;
            a.out[6145] = m;
            a.out[6146] = r;
        }
    }
}

__global__ __launch_bounds__(256) void k_route(RArgs a) {
    cg::grid_group grid = cg::this_grid();
    __shared__ __align__(16) float pool[13344];   // 53376 B -> 2 blocks/CU
    int blk = blockIdx.x, t = threadIdx.x;
    if (blk < 32) ph_attnsm(a, blk, t, pool);
    grid.sync();
    if (blk < 192) ph_Hsum(a, blk, t, pool);
    grid.sync();
    ph_SVj<0, true>(a, blk >> 4, blk & 15, t, pool);
    grid.sync();
    for (int job = blk; job < 1024; job += 512) ph_bup16<false>(a, job, t, pool);
    grid.sync();
    for (int job = blk; job < 768; job += 512) ph_GsSM(a, job, t, pool);
    grid.sync();
    ph_SVj<1, true>(a, blk >> 4, blk & 15, t, pool);
    grid.sync();
    for (int job = blk; job < 1024; job += 512) ph_bup16<true>(a, job, t, pool);
    grid.sync();
    for (int job = blk; job < 768; job += 512) ph_GsSM(a, job, t, pool);
    grid.sync();
    ph_SVj<1, false>(a, blk >> 4, blk & 15, t, pool);
    grid.sync();
    if (blk < 16) ph_u2(a, blk, t, pool);
    grid.sync();
    if (blk < 32) ph_caps2(a, blk, t, pool);
    grid.sync();
    if (blk == 0) ph_final(a, t);
}

extern "C" void kernel_launch(void* const* d_in, const int* in_sizes, int n_in,
                              void* d_out, int out_size, void* d_ws, size_t ws_size,
                              hipStream_t stream) {
    const float* adj   = (const float*)d_in[0];
    const int*   n0    = (const int*)d_in[1];
    const int*   n1    = (const int*)d_in[2];
    const int*   n2    = (const int*)d_in[3];
    const int*   label = (const int*)d_in[4];
    const float* recon = (const float*)d_in[5];
    const float* e0    = (const float*)d_in[6];
    const float* e1    = (const float*)d_in[7];
    const float* e2    = (const float*)d_in[8];
    const float* gw0   = (const float*)d_in[9];
    const float* gb0   = (const float*)d_in[10];
    const float* gw1   = (const float*)d_in[11];
    const float* gb1   = (const float*)d_in[12];
    const float* gw2   = (const float*)d_in[13];
    const float* gb2   = (const float*)d_in[14];
    const float* aw1   = (const float*)d_in[15];
    const float* ab1   = (const float*)d_in[16];
    const float* aw2   = (const float*)d_in[17];
    const float* Wg    = (const float*)d_in[19];
    const float* Wc    = (const float*)d_in[20];
    const float* rw1   = (const float*)d_in[21];
    const float* rb1   = (const float*)d_in[22];
    const float* rw2   = (const float*)d_in[23];
    const float* rb2   = (const float*)d_in[24];
    float* out = (float*)d_out;

    char* p = (char*)d_ws;
    auto alloc = [&](size_t bytes) { char* r = p; p += (bytes + 255) & ~(size_t)255; return r; };
    float*  dinv   = (float*)alloc(NB * NN * 4);
    float*  maskp  = (float*)alloc(NB * NN * 4);
    float*  numn   = (float*)alloc(NB * 4);
    float*  logit  = (float*)alloc(NB * NN * 4);
    float*  bij    = (float*)alloc((size_t)NB * NN * 96 * 4);
    float*  Gs     = (float*)alloc((size_t)NB * 24576 * 4);
    float*  G0     = (float*)alloc(NB * 384 * 4);
    float*  vg     = (float*)alloc(NB * 512 * 4);
    float*  Wv     = (float*)alloc(NB * 6144 * 4);
    float*  u2g    = (float*)alloc(NB * 3072 * 4);
    float*  marg   = (float*)alloc(NB * 4);
    float*  recl   = (float*)alloc(NB * 4);
    int*    deg    = (int*)alloc(NB * NN * 4);
    ushort* nbr    = (ushort*)alloc((size_t)NB * NN * 64 * 2);
    ushort* gwt0h  = (ushort*)alloc(128 * 192 * 2);
    ushort* gwt0l  = (ushort*)alloc(128 * 192 * 2);
    ushort* gwt1h  = (ushort*)alloc(128 * 128 * 2);
    ushort* gwt1l  = (ushort*)alloc(128 * 128 * 2);
    ushort* gwt2h  = (ushort*)alloc(128 * 128 * 2);
    ushort* gwt2l  = (ushort*)alloc(128 * 128 * 2);
    ushort* aw1th  = (ushort*)alloc(384 * 384 * 2);
    ushort* aw1tl  = (ushort*)alloc(384 * 384 * 2);
    float*  Ybuf   = (float*)alloc((size_t)NB * NN * 128 * 4);
    ushort* Hbh    = (ushort*)alloc((size_t)NB * NN * ATT * 2);
    ushort* Hbl    = (ushort*)alloc((size_t)NB * NN * ATT * 2);
    ushort* fbh    = (ushort*)alloc((size_t)NB * NN * GIN * 2);
    ushort* fbl    = (ushort*)alloc((size_t)NB * NN * GIN * 2);

    k_front<<<16960, 256, 0, stream>>>(adj, nbr, deg, dinv, maskp,
                                       n0, n1, n2, e0, e1, e2, fbh, fbl,
                                       gw0, gw1, gw2, aw1,
                                       gwt0h, gwt0l, gwt1h, gwt1l,
                                       gwt2h, gwt2l, aw1th, aw1tl);

    k_mfg<192, 0><<<256, 256, 0, stream>>>(fbh, fbl, 192, gwt0h, gwt0l, gb0, dinv, Ybuf, nullptr);
    k_adjsp<<<1024, 256, 0, stream>>>(nbr, deg, Ybuf, dinv, Hbh, Hbl, 0);
    k_mfg<128, 0><<<256, 256, 0, stream>>>(Hbh, Hbl, ATT, gwt1h, gwt1l, gb1, dinv, Ybuf, nullptr);
    k_adjsp<<<1024, 256, 0, stream>>>(nbr, deg, Ybuf, dinv, Hbh, Hbl, 128);
    k_mfg<128, 0><<<256, 256, 0, stream>>>(Hbh + 128, Hbl + 128, ATT, gwt2h, gwt2l, gb2, dinv, Ybuf, nullptr);
    k_adjsp<<<1024, 256, 0, stream>>>(nbr, deg, Ybuf, dinv, Hbh, Hbl, 256);

    hipMemsetAsync(logit, 0, NB * NN * sizeof(float), stream);
    k_mfg<384, 3><<<dim3(256, 3), 256, 0, stream>>>(Hbh, Hbl, ATT, aw1th, aw1tl, ab1, nullptr,
                                                    logit, aw2);

    RArgs ra;
    ra.logit = logit; ra.maskp = maskp; ra.numn = numn;
    ra.Hbh = Hbh; ra.Hbl = Hbl;
    ra.G0 = G0; ra.Wg = Wg; ra.vg = vg; ra.Wv = Wv;
    ra.bij = bij; ra.Gs = Gs; ra.u2g = u2g; ra.Wc = Wc;
    ra.label = label; ra.recon = recon;
    ra.rw1 = rw1; ra.rb1 = rb1; ra.rw2 = rw2; ra.rb2 = rb2;
    ra.out = out; ra.marg = marg; ra.recl = recl;
    void* kargs[] = { &ra };
    hipLaunchCooperativeKernel((void*)k_route, dim3(512), dim3(256), kargs, 0, stream);
}

// Round 13
// 405.061 us; speedup vs baseline: 2.5835x; 2.5835x over previous
//
#include <hip/hip_runtime.h>
#include <hip/hip_bf16.h>
#include <math.h>

#define NB 32
#define NN 512
#define GIN 192
#define ATT 384
#define EPSF 1e-11f

typedef __attribute__((ext_vector_type(4))) float f32x4;
typedef __attribute__((ext_vector_type(8))) short short8;

__device__ __forceinline__ ushort bfhi(float f) {
    uint u = __float_as_uint(f);
    return (ushort)((u + 0x7FFFu + ((u >> 16) & 1u)) >> 16);
}
__device__ __forceinline__ float bff(ushort h) {
    return __uint_as_float(((uint)h) << 16);
}
__device__ __forceinline__ void bfsplit(float f, ushort& hi, ushort& lo) {
    hi = bfhi(f);
    lo = bfhi(f - bff(hi));
}

// ====== k_front: prep (nbr/deg/dinv/mask) + gather + weight transposes (verified r12) ======
__global__ __launch_bounds__(256) void k_front(
    const float* __restrict__ adj, ushort* __restrict__ nbr, int* __restrict__ deg,
    float* __restrict__ dinv, float* __restrict__ mask,
    const int* __restrict__ n0, const int* __restrict__ n1, const int* __restrict__ n2,
    const float* __restrict__ e0, const float* __restrict__ e1, const float* __restrict__ e2,
    ushort* __restrict__ fh, ushort* __restrict__ fl,
    const float* __restrict__ gw0, const float* __restrict__ gw1,
    const float* __restrict__ gw2, const float* __restrict__ aw1,
    ushort* __restrict__ t0h, ushort* __restrict__ t0l,
    ushort* __restrict__ t1h, ushort* __restrict__ t1l,
    ushort* __restrict__ t2h, ushort* __restrict__ t2l,
    ushort* __restrict__ tah, ushort* __restrict__ tal) {
    __shared__ float tile[32][33];
    int blk = blockIdx.x, t = threadIdx.x;
    if (blk < 4096) {
        int row = blk * 4 + (t >> 6);
        int lane = t & 63;
        const float* a = adj + (size_t)row * NN;
        float4 v0 = ((const float4*)a)[lane * 2];
        float4 v1 = ((const float4*)a)[lane * 2 + 1];
        float vv[8] = {v0.x, v0.y, v0.z, v0.w, v1.x, v1.y, v1.z, v1.w};
        float s = 0.f, m = 0.f;
        int cnt = 0;
        unsigned long long below = (lane == 63) ? 0xFFFFFFFFFFFFFFFFULL >> 1
                                                : ((1ULL << lane) - 1ULL);
#pragma unroll
        for (int e = 0; e < 8; e++) {
            float v = vv[e];
            s += v;
            m = fmaxf(m, v);
            bool nz = v != 0.f;
            unsigned long long bm = __ballot(nz);
            int pos = cnt + __popcll(bm & below);
            if (nz && pos < 64) nbr[(size_t)row * 64 + pos] = (ushort)(lane * 8 + e);
            cnt += __popcll(bm);
        }
        for (int off = 32; off; off >>= 1) {
            s += __shfl_xor(s, off);
            m = fmaxf(m, __shfl_xor(m, off));
        }
        if (lane == 0) {
            deg[row] = cnt < 64 ? cnt : 64;
            dinv[row] = s > 0.f ? 1.0f / sqrtf(s) : 0.f;
            mask[row] = m;
        }
    } else if (blk < 16384) {
        int tid = (blk - 4096) * 256 + t;   // exactly NB*NN*GIN
        int bn = tid / GIN, f = tid - bn * GIN;
        float v;
        if (f < 64)       v = e0[n0[bn] * 64 + f];
        else if (f < 128) v = e1[n1[bn] * 64 + (f - 64)];
        else              v = e2[n2[bn] * 64 + (f - 128)];
        ushort h, lo;
        bfsplit(v, h, lo);
        fh[tid] = h; fl[tid] = lo;
    } else {
        int job = blk - 16384;  // < 576 = 4*144
        int z = job / 144, rem = job % 144;
        int k0 = (rem / 12) * 32, nn0 = (rem % 12) * 32;
        const float* W; ushort *Th, *Tl; int K, N;
        switch (z) {
            case 0: W = gw0; Th = t0h; Tl = t0l; K = 192; N = 128; break;
            case 1: W = gw1; Th = t1h; Tl = t1l; K = 128; N = 128; break;
            case 2: W = gw2; Th = t2h; Tl = t2l; K = 128; N = 128; break;
            default: W = aw1; Th = tah; Tl = tal; K = 384; N = 384; break;
        }
        if (k0 >= K || nn0 >= N) return;
        int tx = t & 31, ty = t >> 5;
#pragma unroll
        for (int r = 0; r < 4; r++)
            tile[ty + r * 8][tx] = W[(size_t)(k0 + ty + r * 8) * N + nn0 + tx];
        __syncthreads();
#pragma unroll
        for (int r = 0; r < 4; r++) {
            int nn = ty + r * 8;
            float v = tile[tx][nn];
            ushort h, lo;
            bfsplit(v, h, lo);
            size_t o = (size_t)(nn0 + nn) * K + k0 + tx;
            Th[o] = h; Tl[o] = lo;
        }
    }
}

// ================= MFMA split-bf16 GEMM: BM=64 x BN=128 (verified r11) =================
template <int KK, int EPI>
__global__ __launch_bounds__(256) void k_mfg(
    const ushort* __restrict__ Ah, const ushort* __restrict__ Al, int lda,
    const ushort* __restrict__ Bh, const ushort* __restrict__ Bl,
    const float* __restrict__ bias, const float* __restrict__ dinv,
    float* __restrict__ Of, const float* __restrict__ aw2p) {
    __shared__ ushort Ash[2048], Asl[2048];
    __shared__ ushort Bsh[4096], Bsl[4096];
    __shared__ float ep[(EPI == 0) ? 64 * 128 : 1];
    int t = threadIdx.x;
    int bid = blockIdx.x;
    {
        int q = gridDim.x >> 3;
        bid = (bid & 7) * q + (bid >> 3);
    }
    int m0 = bid * 64;
    int n0 = blockIdx.y * 128;
    int l = t & 63, w = t >> 6, wr = w >> 1, wc = w & 1;
    int rA = t >> 2, kc = t & 3;
    int rB0 = rA, rB1 = rA + 64;
    int lsA  = ((rA >> 4) * 64 + (rA & 15) + kc * 16) * 8;
    int lsB0 = ((rB0 >> 4) * 64 + (rB0 & 15) + kc * 16) * 8;
    int lsB1 = ((rB1 >> 4) * 64 + (rB1 & 15) + kc * 16) * 8;
    f32x4 z = {0.f, 0.f, 0.f, 0.f};
    f32x4 acc[2][4];
#pragma unroll
    for (int i = 0; i < 2; i++)
#pragma unroll
        for (int j = 0; j < 4; j++) acc[i][j] = z;

    short8 pa0, pal0, pb0, pb1, pbl0, pbl1;
    int kof = kc * 8;
    {
        pa0 = *(const short8*)&Ah[(size_t)(m0 + rA) * lda + kof];
        pal0 = *(const short8*)&Al[(size_t)(m0 + rA) * lda + kof];
        pb0 = *(const short8*)&Bh[(size_t)(n0 + rB0) * KK + kof];
        pb1 = *(const short8*)&Bh[(size_t)(n0 + rB1) * KK + kof];
        pbl0 = *(const short8*)&Bl[(size_t)(n0 + rB0) * KK + kof];
        pbl1 = *(const short8*)&Bl[(size_t)(n0 + rB1) * KK + kof];
    }
    for (int k0 = 0; k0 < KK; k0 += 32) {
        *(short8*)&Ash[lsA] = pa0;
        *(short8*)&Asl[lsA] = pal0;
        *(short8*)&Bsh[lsB0] = pb0;
        *(short8*)&Bsh[lsB1] = pb1;
        *(short8*)&Bsl[lsB0] = pbl0;
        *(short8*)&Bsl[lsB1] = pbl1;
        __syncthreads();
        if (k0 + 32 < KK) {
            int kn = k0 + 32 + kof;
            pa0 = *(const short8*)&Ah[(size_t)(m0 + rA) * lda + kn];
            pal0 = *(const short8*)&Al[(size_t)(m0 + rA) * lda + kn];
            pb0 = *(const short8*)&Bh[(size_t)(n0 + rB0) * KK + kn];
            pb1 = *(const short8*)&Bh[(size_t)(n0 + rB1) * KK + kn];
            pbl0 = *(const short8*)&Bl[(size_t)(n0 + rB0) * KK + kn];
            pbl1 = *(const short8*)&Bl[(size_t)(n0 + rB1) * KK + kn];
        }
        short8 ah[2], al[2], bh[4], bl[4];
#pragma unroll
        for (int i = 0; i < 2; i++) {
            ah[i] = *(const short8*)&Ash[((wr * 2 + i) * 64 + l) * 8];
            al[i] = *(const short8*)&Asl[((wr * 2 + i) * 64 + l) * 8];
        }
#pragma unroll
        for (int j = 0; j < 4; j++) {
            bh[j] = *(const short8*)&Bsh[((wc * 4 + j) * 64 + l) * 8];
            bl[j] = *(const short8*)&Bsl[((wc * 4 + j) * 64 + l) * 8];
        }
#pragma unroll
        for (int i = 0; i < 2; i++)
#pragma unroll
            for (int j = 0; j < 4; j++) {
                acc[i][j] = __builtin_amdgcn_mfma_f32_16x16x32_bf16(ah[i], bh[j], acc[i][j], 0, 0, 0);
                acc[i][j] = __builtin_amdgcn_mfma_f32_16x16x32_bf16(ah[i], bl[j], acc[i][j], 0, 0, 0);
                acc[i][j] = __builtin_amdgcn_mfma_f32_16x16x32_bf16(al[i], bh[j], acc[i][j], 0, 0, 0);
            }
        __syncthreads();
    }
    if constexpr (EPI == 3) {
#pragma unroll
        for (int i = 0; i < 2; i++) {
            float rs[4] = {0.f, 0.f, 0.f, 0.f};
#pragma unroll
            for (int j = 0; j < 4; j++) {
                int gc = n0 + (wc * 4 + j) * 16 + (l & 15);
                float bv = bias[gc], wv = aw2p[gc];
#pragma unroll
                for (int r = 0; r < 4; r++)
                    rs[r] += tanhf(acc[i][j][r] + bv) * wv;
            }
#pragma unroll
            for (int r = 0; r < 4; r++) {
                rs[r] += __shfl_xor(rs[r], 1, 16);
                rs[r] += __shfl_xor(rs[r], 2, 16);
                rs[r] += __shfl_xor(rs[r], 4, 16);
                rs[r] += __shfl_xor(rs[r], 8, 16);
            }
            if ((l & 15) == 0) {
                int gr0 = m0 + (wr * 2 + i) * 16 + 4 * (l >> 4);
#pragma unroll
                for (int r = 0; r < 4; r++) atomicAdd(&Of[gr0 + r], rs[r]);
            }
        }
    } else {
#pragma unroll
        for (int i = 0; i < 2; i++)
#pragma unroll
            for (int j = 0; j < 4; j++) {
                int lc = (wc * 4 + j) * 16 + (l & 15);
                int lr0 = (wr * 2 + i) * 16 + 4 * (l >> 4);
                float bv = bias[lc];
#pragma unroll
                for (int r = 0; r < 4; r++)
                    ep[(lr0 + r) * 128 + lc] = (acc[i][j][r] + bv) * dinv[m0 + lr0 + r];
            }
        __syncthreads();
        int row = t >> 2, c0 = (t & 3) * 32;
        size_t ob = (size_t)(m0 + row) * 128 + c0;
#pragma unroll
        for (int k = 0; k < 8; k++)
            ((float4*)&Of[ob])[k] = *(const float4*)&ep[row * 128 + c0 + k * 4];
    }
}

// ------- sparse adj gather (verified r11): 1024 blocks, 16 rows each -------
__global__ __launch_bounds__(256) void k_adjsp(const ushort* __restrict__ nbr,
                                               const int* __restrict__ deg,
                                               const float* __restrict__ Y,
                                               const float* __restrict__ dinv,
                                               ushort* __restrict__ Hbh,
                                               ushort* __restrict__ Hbl, int hoff) {
    int bid = blockIdx.x;
    {
        int q = gridDim.x >> 3;
        bid = (bid & 7) * q + (bid >> 3);
    }
    int b = bid >> 5;
    int rg = bid & 31;
    int base = b * NN + rg * 16;
    __shared__ ushort nl[16 * 64];
    __shared__ int dl[16];
    int t = threadIdx.x;
    if (t < 128) *(short8*)&nl[t * 8] = *(const short8*)&nbr[(size_t)base * 64 + t * 8];
    if (t < 16) dl[t] = deg[base + t];
    __syncthreads();
    int row = t >> 4, c0 = (t & 15) * 8;
    const float* yp = Y + (size_t)b * 65536 + c0;
    float acc[8] = {0.f, 0.f, 0.f, 0.f, 0.f, 0.f, 0.f, 0.f};
    int dg = dl[row];
    const ushort* nr = &nl[row * 64];
    for (int q = 0; q < dg; q++) {
        const float4* y = (const float4*)(yp + (int)nr[q] * 128);
        float4 a = y[0], c = y[1];
        acc[0] += a.x; acc[1] += a.y; acc[2] += a.z; acc[3] += a.w;
        acc[4] += c.x; acc[5] += c.y; acc[6] += c.z; acc[7] += c.w;
    }
    float dv = dinv[base + row];
    short8 vh, vl;
#pragma unroll
    for (int c = 0; c < 8; c++) {
        float v = tanhf(acc[c] * dv);
        ushort h, lo;
        bfsplit(v, h, lo);
        vh[c] = (short)h; vl[c] = (short)lo;
    }
    size_t o = (size_t)(base + row) * ATT + hoff + c0;
    *(short8*)&Hbh[o] = vh;
    *(short8*)&Hbl[o] = vl;
}

// ------- attention softmax + numn + scale = attn*numn (in-place into logit) -------
__global__ __launch_bounds__(512) void k_attnsm(float* __restrict__ logit,
                                                const float* __restrict__ mask,
                                                float* __restrict__ numn) {
    __shared__ float red[8], red2[8], red3[8];
    int b = blockIdx.x, t = threadIdx.x;
    float mk = mask[b * NN + t];
    float x = mk > 0.f ? logit[b * NN + t] : -INFINITY;
    float m = x, nsum = mk;
    for (int off = 32; off; off >>= 1) {
        m = fmaxf(m, __shfl_xor(m, off));
        nsum += __shfl_xor(nsum, off);
    }
    if ((t & 63) == 0) { red[t >> 6] = m; red3[t >> 6] = nsum; }
    __syncthreads();
    float gm = red[0], nn = red3[0];
    for (int i = 1; i < 8; i++) { gm = fmaxf(gm, red[i]); nn += red3[i]; }
    float e = expf(x - gm);
    float s = e;
    for (int off = 32; off; off >>= 1) s += __shfl_xor(s, off);
    if ((t & 63) == 0) red2[t >> 6] = s;
    __syncthreads();
    float gs = 0.f;
    for (int i = 0; i < 8; i++) gs += red2[i];
    logit[b * NN + t] = (e / gs) * nn;
    if (t == 0) numn[b] = nn;
}

// ------- iter-0: Hsum[b,c,i] = sum_n scale[b,n]*H[b,n,c,i] -------
__global__ __launch_bounds__(256) void k_Hsum(const ushort* __restrict__ Hh,
                                              const ushort* __restrict__ Hl,
                                              const float* __restrict__ scale,
                                              float* __restrict__ G0) {
    int blk = blockIdx.x;  // b*6 + c
    int c = blk % 6, b = blk / 6;
    int t = threadIdx.x;
    int i = t & 63, g = t >> 6;
    float s = 0.f;
    for (int n = g * 128; n < g * 128 + 128; n++) {
        size_t o = ((size_t)b * NN + n) * ATT + c * 64 + i;
        s += scale[b * NN + n] * (bff(Hh[o]) + bff(Hl[o]));
    }
    __shared__ float red[256];
    red[t] = s;
    __syncthreads();
    if (t < 128) red[t] += red[t + 128];
    __syncthreads();
    if (t < 64) G0[(size_t)blk * 64 + i] = red[t] + red[t + 64];
}

// ======= SV per (b,j): Wg_j staged in LDS; optional Wv_j production =======
template <int SRC, bool DOWV>
__global__ __launch_bounds__(256) void k_SVj(const float* __restrict__ gsrc,
                                             const float* __restrict__ Wg,
                                             const float* __restrict__ numn,
                                             float* __restrict__ vg,
                                             float* __restrict__ Wv) {
    int b = blockIdx.x, j = blockIdx.y;
    int t = threadIdx.x;
    __shared__ float Wgl[384 * 33];
    __shared__ float gj[384];
    __shared__ float red[256];
    __shared__ float vvs[32];
    for (int idx = t; idx < 12288; idx += 256) {
        int r = idx >> 5, d = idx & 31;
        Wgl[r * 33 + d] = Wg[(size_t)r * 512 + j * 32 + d];
    }
    for (int r = t; r < 384; r += 256) {
        if constexpr (SRC == 0) {
            gj[r] = gsrc[b * 384 + r] * (1.f / 16.f);
        } else {
            const float* g = gsrc + ((size_t)b * 6 + (r >> 6)) * 4096 + j * 64 + (r & 63);
            gj[r] = g[0] + g[1024] + g[2048] + g[3072];
        }
    }
    __syncthreads();
    int d = t & 31, g8 = t >> 5;
    float pp = 0.f;
#pragma unroll
    for (int k = 0; k < 48; k++) {
        int r = g8 * 48 + k;
        pp += gj[r] * Wgl[r * 33 + d];
    }
    red[t] = pp;
    __syncthreads();
    if (t < 128) red[t] += red[t + 128];
    __syncthreads();
    if (t < 64) red[t] += red[t + 64];
    __syncthreads();
    if (t < 32) {
        float s = (red[t] + red[t + 32]) / numn[b];
        float sq = s * s;
        for (int off = 16; off; off >>= 1) sq += __shfl_xor(sq, off, 32);
        float v = (sq / (1.f + sq)) * s / sqrtf(sq + EPSF);
        vvs[t] = v;
        vg[(size_t)b * 512 + j * 32 + t] = v;
    }
    __syncthreads();
    if constexpr (DOWV) {
        for (int r = t; r < 384; r += 256) {
            float a = 0.f;
#pragma unroll
            for (int d2 = 0; d2 < 32; d2++) a += Wgl[r * 33 + d2] * vvs[d2];
            Wv[(size_t)b * 6144 + (r >> 6) * 1024 + (r & 63) * 16 + j] = a;
        }
    }
}

// ------- Gs with inline softmax over bij (scaled H) -------
__global__ __launch_bounds__(256) void k_GsSM(const float* __restrict__ bij,
                                              const ushort* __restrict__ Hh,
                                              const ushort* __restrict__ Hl,
                                              const float* __restrict__ scale,
                                              float* __restrict__ Gs) {
    int blk = blockIdx.x;  // b*24 + c*4 + seg
    int seg = blk & 3, c = (blk >> 2) % 6, b = blk / 24;
    __shared__ float ct[16 * 16];
    __shared__ float ht[16 * 64];
    int t = threadIdx.x;
    int i = t & 63, j0 = t >> 6;
    float acc[4] = {0.f, 0.f, 0.f, 0.f};
    int n0 = seg * 128;
    for (int nc = 0; nc < 128; nc += 16) {
        {
            int nn = t >> 4;
            float v = bij[(((size_t)b * NN + n0 + nc + nn) * 6 + c) * 16 + (t & 15)];
            float mx = v;
            mx = fmaxf(mx, __shfl_xor(mx, 1, 16));
            mx = fmaxf(mx, __shfl_xor(mx, 2, 16));
            mx = fmaxf(mx, __shfl_xor(mx, 4, 16));
            mx = fmaxf(mx, __shfl_xor(mx, 8, 16));
            float e = expf(v - mx);
            float sm = e;
            sm += __shfl_xor(sm, 1, 16);
            sm += __shfl_xor(sm, 2, 16);
            sm += __shfl_xor(sm, 4, 16);
            sm += __shfl_xor(sm, 8, 16);
            ct[t] = e / sm;
        }
        for (int idx = t; idx < 1024; idx += 256) {
            int nn = idx >> 6, ii = idx & 63;
            int n = n0 + nc + nn;
            size_t o = ((size_t)b * NN + n) * ATT + c * 64 + ii;
            ht[idx] = scale[b * NN + n] * (bff(Hh[o]) + bff(Hl[o]));
        }
        __syncthreads();
        for (int nn = 0; nn < 16; nn++) {
            float hv = ht[nn * 64 + i];
#pragma unroll
            for (int q = 0; q < 4; q++) acc[q] += ct[nn * 16 + j0 * 4 + q] * hv;
        }
        __syncthreads();
    }
#pragma unroll
    for (int q = 0; q < 4; q++) {
        int j = j0 * 4 + q;
        Gs[(((size_t)b * 6 + c) * 4 + seg) * 1024 + j * 64 + i] = acc[q];
    }
}

// ------- b_ij (=|+=) sum_i scale*H[b,n,c,i]*Wv[b,c,i,j] -------
template <bool ACC>
__global__ __launch_bounds__(256) void k_bup(const ushort* __restrict__ Hh,
                                             const ushort* __restrict__ Hl,
                                             const float* __restrict__ scale,
                                             const float* __restrict__ Wv,
                                             float* __restrict__ bij) {
    int blk = blockIdx.x;
    int b = blk >> 4;
    int n0 = (blk & 15) * 32;
    __shared__ float wl[6144];
    __shared__ float hl[32 * ATT];
    int t = threadIdx.x;
    for (int idx = t; idx < 6144; idx += 256) wl[idx] = Wv[(size_t)b * 6144 + idx];
    for (int idx = t; idx < 32 * ATT; idx += 256) {
        int nn = idx / ATT;
        size_t o = ((size_t)b * NN + n0) * ATT + idx;
        hl[idx] = scale[b * NN + n0 + nn] * (bff(Hh[o]) + bff(Hl[o]));
    }
    __syncthreads();
    for (int idx = t; idx < 3072; idx += 256) {
        int nn = idx / 96, r = idx % 96, c = r >> 4, j = r & 15;
        float a = 0.f;
        const float* h = hl + nn * ATT + c * 64;
        const float* w = wl + c * 1024 + j;
#pragma unroll
        for (int i2 = 0; i2 < 64; i2++) a += h[i2] * w[i2 * 16];
        size_t o = (((size_t)b * NN + n0 + nn) * 6 + c) * 16 + j;
        if constexpr (ACC) bij[o] += a;
        else bij[o] = a;
    }
}

// ------- u2[b, c*192 + j*32+d] = sum_i2 vg[b,c*32+i2] * Wc[c, i2, j*32+d] -------
__global__ __launch_bounds__(256) void k_u2(const float* __restrict__ vg,
                                            const float* __restrict__ Wc,
                                            float* __restrict__ u2g) {
    int c = blockIdx.x;  // 16
    int t = threadIdx.x;
    __shared__ float Wcl[32 * 192];
    __shared__ float vgl[32 * 32];
    for (int idx = t; idx < 6144; idx += 256)
        Wcl[idx] = Wc[(size_t)c * 6144 + idx];
    for (int idx = t; idx < 1024; idx += 256) {
        int b = idx >> 5, i2 = idx & 31;
        vgl[idx] = vg[(size_t)b * 512 + c * 32 + i2];
    }
    __syncthreads();
    for (int o = t; o < 6144; o += 256) {
        int b = o / 192, jd = o - b * 192;
        float a = 0.f;
#pragma unroll
        for (int i2 = 0; i2 < 32; i2++) a += vgl[b * 32 + i2] * Wcl[i2 * 192 + jd];
        u2g[(size_t)b * 3072 + c * 192 + jd] = a;
    }
}

// ---------------- second routing + losses, one block per batch ----------------
__global__ __launch_bounds__(256) void k_caps2(
    const float* __restrict__ u2g,
    const int* __restrict__ label, const float* __restrict__ recon_in,
    const float* __restrict__ rw1, const float* __restrict__ rb1,
    const float* __restrict__ rw2, const float* __restrict__ rb2,
    float* __restrict__ out, float* __restrict__ marg, float* __restrict__ reconl) {
    int b = blockIdx.x, t = threadIdx.x;
    __shared__ float u2[3072];
    __shared__ float b2[96], c2b[96];
    __shared__ float vv[192];
    __shared__ float magl[6];
    __shared__ float cm[32];
    __shared__ float hidl[128];
    __shared__ float red[256];
    for (int idx = t; idx < 3072; idx += 256) u2[idx] = u2g[(size_t)b * 3072 + idx];
    if (t < 96) b2[t] = 0.f;
    __syncthreads();
    for (int it = 0; it < 3; it++) {
        if (t < 16) {
            float mx = -INFINITY;
            for (int j = 0; j < 6; j++) mx = fmaxf(mx, b2[t * 6 + j]);
            float e[6], s = 0.f;
            for (int j = 0; j < 6; j++) { e[j] = expf(b2[t * 6 + j] - mx); s += e[j]; }
            for (int j = 0; j < 6; j++) c2b[t * 6 + j] = e[j] / s;
        }
        __syncthreads();
        if (t < 192) {
            int j = t >> 5, d = t & 31;
            float s = 0.f;
            for (int c = 0; c < 16; c++) s += c2b[c * 6 + j] * u2[c * 192 + j * 32 + d];
            float sq = s * s;
            for (int off = 16; off; off >>= 1) sq += __shfl_xor(sq, off, 32);
            vv[t] = (sq / (1.f + sq)) * s / sqrtf(sq + EPSF);
        }
        __syncthreads();
        if (it < 2) {
            if (t < 96) {
                int c = t / 6, j = t - c * 6;
                float a = 0.f;
                for (int d = 0; d < 32; d++) a += u2[c * 192 + j * 32 + d] * vv[j * 32 + d];
                b2[t] += a;
            }
            __syncthreads();
        }
    }
    if (t < 192) out[(size_t)b * 192 + t] = vv[t];
    if (t < 6) {
        float s = 0.f;
        for (int d = 0; d < 32; d++) { float v = vv[t * 32 + d]; s += v * v; }
        magl[t] = sqrtf(s);
    }
    __syncthreads();
    int lab = label[b];
    if (t == 0) {
        float L = 0.f;
        int p = 0;
        float best = magl[0];
        for (int j = 0; j < 6; j++) {
            float mg = magl[j];
            if (mg > best) { best = mg; p = j; }
            float ml = fmaxf(0.9f - mg, 0.f); ml *= ml;
            float mr = fmaxf(mg - 0.1f, 0.f); mr *= mr;
            L += (j == lab) ? ml : 0.5f * mr;
        }
        marg[b] = L;
        out[6147 + b] = (float)p;
    }
    if (t < 32) cm[t] = vv[lab * 32 + t];
    __syncthreads();
    if (t < 128) {
        float a = rb1[t];
        for (int d = 0; d < 32; d++) a += cm[d] * rw1[d * 128 + t];
        hidl[t] = fmaxf(a, 0.f);
    }
    __syncthreads();
    bool act = t < 208;
    float rv = 0.f, rin = 0.f;
    if (act) {
        float a = rb2[t];
        for (int k = 0; k < 128; k++) a += hidl[k] * rw2[k * 208 + t];
        rv = 1.f / (1.f + expf(-a));
        rin = recon_in[(size_t)b * 208 + t];
    }
    red[t] = act ? rin : -INFINITY;
    __syncthreads();
    for (int s2 = 128; s2; s2 >>= 1) {
        if (t < s2) red[t] = fmaxf(red[t], red[t + s2]);
        __syncthreads();
    }
    float rmax = red[0];
    __syncthreads();
    float dpos = 0.f, dneg = 0.f;
    if (act) {
        float rec_val = rin / (rmax + EPSF);
        float d2 = rv - rec_val; d2 *= d2;
        bool neg = rin < 1e-5f;
        dpos = neg ? 0.f : d2;
        dneg = neg ? d2 : 0.f;
    }
    red[t] = dpos;
    __syncthreads();
    for (int s2 = 128; s2; s2 >>= 1) {
        if (t < s2) red[t] = fmaxf(red[t], red[t + s2]);
        __syncthreads();
    }
    float mp = red[0];
    __syncthreads();
    red[t] = dneg;
    __syncthreads();
    for (int s2 = 128; s2; s2 >>= 1) {
        if (t < s2) red[t] = fmaxf(red[t], red[t + s2]);
        __syncthreads();
    }
    if (t == 0) reconl[b] = mp + red[0];
}

__global__ void k_final(const float* __restrict__ marg, const float* __restrict__ reconl,
                        float* __restrict__ out) {
    int t = threadIdx.x;  // 64
    float m = (t < 32) ? marg[t] : 0.f;
    float r = (t < 32) ? reconl[t] : 0.f;
    for (int off = 16; off; off >>= 1) { m += __shfl_xor(m, off, 32); r += __shfl_xor(r, off, 32); }
    if (t == 0) {
        m /= 32.f;
        r /= 32.f;
        out[6144] = m + 0.1f * r;
        out[6145] = m;
        out[6146] = r;
    }
}

extern "C" void kernel_launch(void* const* d_in, const int* in_sizes, int n_in,
                              void* d_out, int out_size, void* d_ws, size_t ws_size,
                              hipStream_t stream) {
    const float* adj   = (const float*)d_in[0];
    const int*   n0    = (const int*)d_in[1];
    const int*   n1    = (const int*)d_in[2];
    const int*   n2    = (const int*)d_in[3];
    const int*   label = (const int*)d_in[4];
    const float* recon = (const float*)d_in[5];
    const float* e0    = (const float*)d_in[6];
    const float* e1    = (const float*)d_in[7];
    const float* e2    = (const float*)d_in[8];
    const float* gw0   = (const float*)d_in[9];
    const float* gb0   = (const float*)d_in[10];
    const float* gw1   = (const float*)d_in[11];
    const float* gb1   = (const float*)d_in[12];
    const float* gw2   = (const float*)d_in[13];
    const float* gb2   = (const float*)d_in[14];
    const float* aw1   = (const float*)d_in[15];
    const float* ab1   = (const float*)d_in[16];
    const float* aw2   = (const float*)d_in[17];
    const float* Wg    = (const float*)d_in[19];
    const float* Wc    = (const float*)d_in[20];
    const float* rw1   = (const float*)d_in[21];
    const float* rb1   = (const float*)d_in[22];
    const float* rw2   = (const float*)d_in[23];
    const float* rb2   = (const float*)d_in[24];
    float* out = (float*)d_out;

    char* p = (char*)d_ws;
    auto alloc = [&](size_t bytes) { char* r = p; p += (bytes + 255) & ~(size_t)255; return r; };
    float*  dinv   = (float*)alloc(NB * NN * 4);
    float*  maskp  = (float*)alloc(NB * NN * 4);
    float*  numn   = (float*)alloc(NB * 4);
    float*  logit  = (float*)alloc(NB * NN * 4);
    float*  bij    = (float*)alloc((size_t)NB * NN * 96 * 4);
    float*  Gs     = (float*)alloc((size_t)NB * 24576 * 4);
    float*  G0     = (float*)alloc(NB * 384 * 4);
    float*  vg     = (float*)alloc(NB * 512 * 4);
    float*  Wv     = (float*)alloc(NB * 6144 * 4);
    float*  u2g    = (float*)alloc(NB * 3072 * 4);
    float*  marg   = (float*)alloc(NB * 4);
    float*  recl   = (float*)alloc(NB * 4);
    int*    deg    = (int*)alloc(NB * NN * 4);
    ushort* nbr    = (ushort*)alloc((size_t)NB * NN * 64 * 2);
    ushort* gwt0h  = (ushort*)alloc(128 * 192 * 2);
    ushort* gwt0l  = (ushort*)alloc(128 * 192 * 2);
    ushort* gwt1h  = (ushort*)alloc(128 * 128 * 2);
    ushort* gwt1l  = (ushort*)alloc(128 * 128 * 2);
    ushort* gwt2h  = (ushort*)alloc(128 * 128 * 2);
    ushort* gwt2l  = (ushort*)alloc(128 * 128 * 2);
    ushort* aw1th  = (ushort*)alloc(384 * 384 * 2);
    ushort* aw1tl  = (ushort*)alloc(384 * 384 * 2);
    float*  Ybuf   = (float*)alloc((size_t)NB * NN * 128 * 4);
    ushort* Hbh    = (ushort*)alloc((size_t)NB * NN * ATT * 2);
    ushort* Hbl    = (ushort*)alloc((size_t)NB * NN * ATT * 2);
    ushort* fbh    = (ushort*)alloc((size_t)NB * NN * GIN * 2);
    ushort* fbl    = (ushort*)alloc((size_t)NB * NN * GIN * 2);

    k_front<<<16960, 256, 0, stream>>>(adj, nbr, deg, dinv, maskp,
                                       n0, n1, n2, e0, e1, e2, fbh, fbl,
                                       gw0, gw1, gw2, aw1,
                                       gwt0h, gwt0l, gwt1h, gwt1l,
                                       gwt2h, gwt2l, aw1th, aw1tl);

    k_mfg<192, 0><<<256, 256, 0, stream>>>(fbh, fbl, 192, gwt0h, gwt0l, gb0, dinv, Ybuf, nullptr);
    k_adjsp<<<1024, 256, 0, stream>>>(nbr, deg, Ybuf, dinv, Hbh, Hbl, 0);
    k_mfg<128, 0><<<256, 256, 0, stream>>>(Hbh, Hbl, ATT, gwt1h, gwt1l, gb1, dinv, Ybuf, nullptr);
    k_adjsp<<<1024, 256, 0, stream>>>(nbr, deg, Ybuf, dinv, Hbh, Hbl, 128);
    k_mfg<128, 0><<<256, 256, 0, stream>>>(Hbh + 128, Hbl + 128, ATT, gwt2h, gwt2l, gb2, dinv, Ybuf, nullptr);
    k_adjsp<<<1024, 256, 0, stream>>>(nbr, deg, Ybuf, dinv, Hbh, Hbl, 256);

    hipMemsetAsync(logit, 0, NB * NN * sizeof(float), stream);
    k_mfg<384, 3><<<dim3(256, 3), 256, 0, stream>>>(Hbh, Hbl, ATT, aw1th, aw1tl, ab1, nullptr,
                                                    logit, aw2);
    k_attnsm<<<NB, 512, 0, stream>>>(logit, maskp, numn);

    // routing iter 0 (c uniform = 1/16)
    k_Hsum<<<NB * 6, 256, 0, stream>>>(Hbh, Hbl, logit, G0);
    k_SVj<0, true><<<dim3(NB, 16), 256, 0, stream>>>(G0, Wg, numn, vg, Wv);
    k_bup<false><<<NB * 16, 256, 0, stream>>>(Hbh, Hbl, logit, Wv, bij);
    // iter 1
    k_GsSM<<<NB * 24, 256, 0, stream>>>(bij, Hbh, Hbl, logit, Gs);
    k_SVj<1, true><<<dim3(NB, 16), 256, 0, stream>>>(Gs, Wg, numn, vg, Wv);
    k_bup<true><<<NB * 16, 256, 0, stream>>>(Hbh, Hbl, logit, Wv, bij);
    // iter 2
    k_GsSM<<<NB * 24, 256, 0, stream>>>(bij, Hbh, Hbl, logit, Gs);
    k_SVj<1, false><<<dim3(NB, 16), 256, 0, stream>>>(Gs, Wg, numn, vg, nullptr);

    k_u2<<<16, 256, 0, stream>>>(vg, Wc, u2g);
    k_caps2<<<NB, 256, 0, stream>>>(u2g, label, recon, rw1, rb1, rw2, rb2, out, marg, recl);
    k_final<<<1, 64, 0, stream>>>(marg, recl, out);
}